// Round 1
// baseline (7843.894 us; speedup 1.0000x reference)
//
#include <hip/hip_runtime.h>
#include <hip/hip_bf16.h>
#include <math.h>

#define VOCAB  32000
#define DMODEL 1024
#define NLAYER 4
#define SEQT   1024
#define BATCH  2
#define EINNER 2048
#define NSTATE 16
#define DTRANK 64
#define KCONV  4
#define NTOK   (BATCH*SEQT)   // 2048
#define XDBLW  (DTRANK + 2*NSTATE)  // 96

// ---------------------------------------------------------------------------
// Generic GEMM: C[m,n] (op)= sum_k A[m*lda+k] * W[n*ldw+k]
// EPI: 0 = store, 1 = store softplus(acc + bias[n]), 2 = C[m,n] += acc
// Tiles: 64x64, BK=16, 256 threads, 4x4 micro-tile per thread.
// K must be a multiple of 16; M,N guarded.
// ---------------------------------------------------------------------------
template<int EPI>
__global__ __launch_bounds__(256) void gemm_tn(
    const float* __restrict__ A, int lda,
    const float* __restrict__ W, int ldw,
    float* __restrict__ C, int ldc,
    const float* __restrict__ bias,
    int M, int N, int K)
{
  __shared__ float As[16][68];   // k-major, padded for 16B-aligned b128 reads
  __shared__ float Ws[16][68];

  const int tid = threadIdx.x;
  const int tx = tid & 15, ty = tid >> 4;
  const int m0 = blockIdx.y * 64, n0 = blockIdx.x * 64;

  float acc[4][4];
  #pragma unroll
  for (int i = 0; i < 4; ++i)
    #pragma unroll
    for (int j = 0; j < 4; ++j) acc[i][j] = 0.f;

  const int lr = tid >> 2;          // 0..63 tile row
  const int lc = (tid & 3) << 2;    // 0,4,8,12

  for (int k0 = 0; k0 < K; k0 += 16) {
    float4 av = make_float4(0.f,0.f,0.f,0.f);
    float4 wv = make_float4(0.f,0.f,0.f,0.f);
    if (m0 + lr < M) av = *(const float4*)(A + (size_t)(m0+lr)*lda + k0 + lc);
    if (n0 + lr < N) wv = *(const float4*)(W + (size_t)(n0+lr)*ldw + k0 + lc);
    As[lc+0][lr]=av.x; As[lc+1][lr]=av.y; As[lc+2][lr]=av.z; As[lc+3][lr]=av.w;
    Ws[lc+0][lr]=wv.x; Ws[lc+1][lr]=wv.y; Ws[lc+2][lr]=wv.z; Ws[lc+3][lr]=wv.w;
    __syncthreads();
    #pragma unroll
    for (int kk = 0; kk < 16; ++kk) {
      float a[4], w[4];
      *(float4*)a = *(const float4*)&As[kk][ty<<2];
      *(float4*)w = *(const float4*)&Ws[kk][tx<<2];
      #pragma unroll
      for (int i = 0; i < 4; ++i)
        #pragma unroll
        for (int j = 0; j < 4; ++j)
          acc[i][j] += a[i]*w[j];
    }
    __syncthreads();
  }

  #pragma unroll
  for (int i = 0; i < 4; ++i) {
    int m = m0 + (ty<<2) + i;
    if (m >= M) continue;
    #pragma unroll
    for (int j = 0; j < 4; ++j) {
      int n = n0 + (tx<<2) + j;
      if (n >= N) continue;
      float v = acc[i][j];
      size_t idx = (size_t)m*ldc + n;
      if (EPI == 0) {
        C[idx] = v;
      } else if (EPI == 1) {
        v += bias[n];
        C[idx] = (v > 20.f) ? v : log1pf(expf(v));
      } else {
        C[idx] += v;
      }
    }
  }
}

// ---------------------------------------------------------------------------
__global__ __launch_bounds__(256) void embed_kernel(
    const int* __restrict__ ids, const float* __restrict__ tok,
    const float* __restrict__ pos, float* __restrict__ x)
{
  int row = blockIdx.x;           // b*T + t
  int t = row & (SEQT-1);
  int id = ids[row];
  const float4* te = (const float4*)(tok + (size_t)id*DMODEL);
  const float4* pe = (const float4*)(pos + (size_t)t*DMODEL);
  float4* xo = (float4*)(x + (size_t)row*DMODEL);
  int i = threadIdx.x;            // D/4 == 256
  float4 a = te[i], b = pe[i];
  xo[i] = make_float4(a.x+b.x, a.y+b.y, a.z+b.z, a.w+b.w);
}

// causal depthwise conv (K=4) + bias + silu.  xz row = [xc(0..E) | z(E..2E)]
__global__ __launch_bounds__(256) void conv_silu_kernel(
    const float* __restrict__ xz, const float* __restrict__ w,
    const float* __restrict__ b, float* __restrict__ xc)
{
  size_t i = (size_t)blockIdx.x*256 + threadIdx.x;  // < NTOK*E
  int e = (int)(i & (EINNER-1));
  int row = (int)(i >> 11);       // EINNER = 2^11
  int t = row & (SEQT-1);
  float acc = b[e];
  #pragma unroll
  for (int k = 0; k < KCONV; ++k) {
    int tt = t - (KCONV-1) + k;
    if (tt >= 0)
      acc += w[e*KCONV + k] * xz[(size_t)(row - (KCONV-1) + k)*(2*EINNER) + e];
  }
  float sg = 1.f / (1.f + expf(-acc));
  xc[i] = acc * sg;
}

// selective scan: thread per (b,e,n); 16-lane shfl reduction over n.
// Fuses y = (scan + D*xc) * silu(z).
__global__ __launch_bounds__(256) void scan_kernel(
    const float* __restrict__ delta, const float* __restrict__ xc,
    const float* __restrict__ xdbl,  const float* __restrict__ alog,
    const float* __restrict__ dpar,  const float* __restrict__ xz,
    float* __restrict__ y)
{
  int gid = blockIdx.x*256 + threadIdx.x;
  int n  = gid & (NSTATE-1);
  int eg = gid >> 4;              // b*E + e
  int e  = eg & (EINNER-1);
  int b  = eg >> 11;
  if (b >= BATCH) return;

  float A = -expf(alog[e*NSTATE + n]);
  float Dv = dpar[e];
  float h = 0.f;
  for (int t = 0; t < SEQT; ++t) {
    int row = b*SEQT + t;
    size_t re = (size_t)row*EINNER + e;
    size_t rx = (size_t)row*XDBLW;
    float dl  = delta[re];
    float xcv = xc[re];
    float Bv  = xdbl[rx + DTRANK + n];
    float Cv  = xdbl[rx + DTRANK + NSTATE + n];
    float dA  = expf(dl * A);
    h = dA*h + dl*Bv*xcv;
    float p = h*Cv;
    p += __shfl_xor(p, 1);
    p += __shfl_xor(p, 2);
    p += __shfl_xor(p, 4);
    p += __shfl_xor(p, 8);
    if (n == 0) {
      float zv = xz[(size_t)row*(2*EINNER) + EINNER + e];
      float sz = zv / (1.f + expf(-zv));
      y[re] = (p + Dv*xcv) * sz;
    }
  }
}

__global__ __launch_bounds__(256) void ln_kernel(
    const float* __restrict__ x, const float* __restrict__ g,
    const float* __restrict__ bt, float* __restrict__ xn)
{
  int row = blockIdx.x;
  const float4* xr = (const float4*)(x + (size_t)row*DMODEL);
  int i = threadIdx.x;            // D/4 == 256
  float4 v = xr[i];
  float s  = v.x+v.y+v.z+v.w;
  float s2 = v.x*v.x+v.y*v.y+v.z*v.z+v.w*v.w;
  #pragma unroll
  for (int o = 1; o < 64; o <<= 1) { s += __shfl_xor(s,o); s2 += __shfl_xor(s2,o); }
  __shared__ float ss[4], ss2[4];
  if ((threadIdx.x & 63) == 0) { ss[threadIdx.x>>6] = s; ss2[threadIdx.x>>6] = s2; }
  __syncthreads();
  s  = ss[0]+ss[1]+ss[2]+ss[3];
  s2 = ss2[0]+ss2[1]+ss2[2]+ss2[3];
  float mean = s * (1.f/DMODEL);
  float var  = s2 * (1.f/DMODEL) - mean*mean;
  float r = rsqrtf(var + 1e-5f);
  const float4* gg = (const float4*)g;
  const float4* bb = (const float4*)bt;
  float4 gv = gg[i], bv = bb[i];
  float4 o;
  o.x = (v.x-mean)*r*gv.x + bv.x;
  o.y = (v.y-mean)*r*gv.y + bv.y;
  o.z = (v.z-mean)*r*gv.z + bv.z;
  o.w = (v.w-mean)*r*gv.w + bv.w;
  ((float4*)(xn + (size_t)row*DMODEL))[i] = o;
}

__global__ void zero_kernel(float* p) { if (threadIdx.x < 8) p[threadIdx.x] = 0.f; }

__global__ __launch_bounds__(256) void loss_kernel(
    const float* __restrict__ logits, const int* __restrict__ tgt, float* acc)
{
  int row = blockIdx.x;
  const float4* lr = (const float4*)(logits + (size_t)row*VOCAB);
  float mx = -1e30f;
  for (int i = threadIdx.x; i < VOCAB/4; i += 256) {
    float4 v = lr[i];
    mx = fmaxf(mx, fmaxf(fmaxf(v.x,v.y), fmaxf(v.z,v.w)));
  }
  #pragma unroll
  for (int o = 1; o < 64; o <<= 1) mx = fmaxf(mx, __shfl_xor(mx, o));
  __shared__ float sred[4];
  if ((threadIdx.x & 63) == 0) sred[threadIdx.x>>6] = mx;
  __syncthreads();
  mx = fmaxf(fmaxf(sred[0], sred[1]), fmaxf(sred[2], sred[3]));
  __syncthreads();
  float s = 0.f;
  for (int i = threadIdx.x; i < VOCAB/4; i += 256) {
    float4 v = lr[i];
    s += expf(v.x-mx) + expf(v.y-mx) + expf(v.z-mx) + expf(v.w-mx);
  }
  #pragma unroll
  for (int o = 1; o < 64; o <<= 1) s += __shfl_xor(s, o);
  if ((threadIdx.x & 63) == 0) sred[threadIdx.x>>6] = s;
  __syncthreads();
  if (threadIdx.x == 0) {
    float ssum = sred[0]+sred[1]+sred[2]+sred[3];
    int t = tgt[row];
    if (t != -100) {
      float lp = logits[(size_t)row*VOCAB + t] - mx - logf(ssum);
      atomicAdd(&acc[0], -lp);
      atomicAdd(&acc[1], 1.f);
    }
  }
}

__global__ void finalize_loss(const float* acc, float* out) {
  out[0] = acc[0] / fmaxf(acc[1], 1.f);
}

// ---------------------------------------------------------------------------
extern "C" void kernel_launch(void* const* d_in, const int* in_sizes, int n_in,
                              void* d_out, int out_size, void* d_ws, size_t ws_size,
                              hipStream_t stream)
{
  (void)in_sizes; (void)n_in; (void)out_size; (void)ws_size;
  const int*   ids   = (const int*)d_in[0];
  const int*   tgts  = (const int*)d_in[1];
  const float* tok   = (const float*)d_in[2];
  const float* pos   = (const float*)d_in[3];
  const float* lng   = (const float*)d_in[4];
  const float* lnb   = (const float*)d_in[5];
  const float* headw = (const float*)d_in[6];
  const float* ipw   = (const float*)d_in[7];
  const float* cw    = (const float*)d_in[8];
  const float* cb    = (const float*)d_in[9];
  const float* xpw   = (const float*)d_in[10];
  const float* dtw   = (const float*)d_in[11];
  const float* dtb   = (const float*)d_in[12];
  const float* alog  = (const float*)d_in[13];
  const float* dpar  = (const float*)d_in[14];
  const float* opw   = (const float*)d_in[15];

  float* out = (float*)d_out;
  // transient scratch inside d_out (logits overwrite it at the end):
  float* xz    = out;                 //  8,388,608  [NTOK][2E]
  float* xc    = out + 8388608;       //  4,194,304  [NTOK][E]
  float* delta = out + 12582912;      //  4,194,304  [NTOK][E]
  float* y     = out + 16777216;      //  4,194,304  [NTOK][E]
  float* x     = out + 20971520;      //  2,097,152  [NTOK][D]
  float* xdbl  = out + 23068672;      //    196,608  [NTOK][96]
  // persistent-past-head buffers in ws:
  float* xn      = (float*)d_ws;      //  2,097,152  [NTOK][D]
  float* lossacc = (float*)d_ws + 2097152;

  embed_kernel<<<NTOK, 256, 0, stream>>>(ids, tok, pos, x);

  for (int l = 0; l < NLAYER; ++l) {
    // xz = x @ in_proj^T   [2048 x 4096 x 1024]
    gemm_tn<0><<<dim3((2*EINNER)/64, NTOK/64), 256, 0, stream>>>(
        x, DMODEL, ipw + (size_t)l*2*EINNER*DMODEL, DMODEL,
        xz, 2*EINNER, nullptr, NTOK, 2*EINNER, DMODEL);
    // xc = silu(causal_conv(xz[:, :E]) + cb)
    conv_silu_kernel<<<(NTOK*EINNER)/256, 256, 0, stream>>>(
        xz, cw + (size_t)l*EINNER*KCONV, cb + (size_t)l*EINNER, xc);
    // xdbl = xc @ x_proj^T  [2048 x 96 x 2048]
    gemm_tn<0><<<dim3(2, NTOK/64), 256, 0, stream>>>(
        xc, EINNER, xpw + (size_t)l*XDBLW*EINNER, EINNER,
        xdbl, XDBLW, nullptr, NTOK, XDBLW, EINNER);
    // delta = softplus(xdbl[:, :R] @ dt_proj^T + dtb)  [2048 x 2048 x 64]
    gemm_tn<1><<<dim3(EINNER/64, NTOK/64), 256, 0, stream>>>(
        xdbl, XDBLW, dtw + (size_t)l*EINNER*DTRANK, DTRANK,
        delta, EINNER, dtb + (size_t)l*EINNER, NTOK, EINNER, DTRANK);
    // y = (selective_scan + D*xc) * silu(z)
    scan_kernel<<<(BATCH*EINNER*NSTATE)/256, 256, 0, stream>>>(
        delta, xc, xdbl, alog + (size_t)l*EINNER*NSTATE,
        dpar + (size_t)l*EINNER, xz, y);
    // x += y @ out_proj^T   [2048 x 1024 x 2048]
    gemm_tn<2><<<dim3(DMODEL/64, NTOK/64), 256, 0, stream>>>(
        y, EINNER, opw + (size_t)l*DMODEL*EINNER, EINNER,
        x, DMODEL, nullptr, NTOK, DMODEL, EINNER);
  }

  ln_kernel<<<NTOK, 256, 0, stream>>>(x, lng, lnb, xn);

  // logits = xn @ head_w^T  [2048 x 32000 x 1024]  -> overwrites all scratch
  gemm_tn<0><<<dim3(VOCAB/64, NTOK/64), 256, 0, stream>>>(
      xn, DMODEL, headw, DMODEL, out, VOCAB, nullptr, NTOK, VOCAB, DMODEL);

  zero_kernel<<<1, 64, 0, stream>>>(lossacc);
  loss_kernel<<<NTOK, 256, 0, stream>>>(out, tgts, lossacc);
  finalize_loss<<<1, 1, 0, stream>>>(lossacc, out + (size_t)NTOK*VOCAB);
}